// Round 4
// baseline (140.985 us; speedup 1.0000x reference)
//
#include <hip/hip_runtime.h>
#include <math.h>

// Shapes fixed by the reference: x [B=16, C=512, N=4096] fp32.
constexpr int B  = 16;
constexpr int C  = 512;
constexpr int N  = 4096;
constexpr int CR = 128;   // C/4
constexpr int NT = 64;    // n-tile per k_main block
constexpr int KC = 64;    // c-chunk per staging step

typedef __attribute__((ext_vector_type(8))) short bf16x8;
typedef __attribute__((ext_vector_type(4))) float f32x4;

__device__ __forceinline__ float sigmoidf_(float v) {
    return 1.0f / (1.0f + __expf(-v));
}
// fp32 -> bf16 round-to-nearest-even
__device__ __forceinline__ unsigned f2bf(float f) {
    unsigned u = __float_as_uint(f);
    u += 0x7fffu + ((u >> 16) & 1u);
    return u >> 16;
}

// lgkmcnt(0) + raw barrier: makes LDS writes visible WITHOUT draining vmcnt,
// so prefetched global loads stay in flight across the barrier (anti-m97-stall).
#define LGKM_BARRIER() do {                                   \
    asm volatile("s_waitcnt lgkmcnt(0)" ::: "memory");        \
    __builtin_amdgcn_s_barrier();                             \
    asm volatile("" ::: "memory");                            \
} while (0)

// ---------------------------------------------------------------------------
// k_pre: fused  (blocks 0..2047) pooled[b][c] = mean_n x[b][c][n]
//               (blocks 2048..2079) BN-fold w3 -> bf16 swizzled w3s + bias2
// w3s byte layout: ck*16384 + ((o*128 + c_lo*2) ^ ((o&7)<<4))  (chunk-major)
// ---------------------------------------------------------------------------
__global__ __launch_bounds__(256) void k_pre(
    const float* __restrict__ x, float* __restrict__ pooled,
    const float* __restrict__ w3, const float* __restrict__ b3,
    const float* __restrict__ gamma, const float* __restrict__ beta,
    const float* __restrict__ mean, const float* __restrict__ var,
    unsigned short* __restrict__ w3s, float* __restrict__ bias2)
{
    if (blockIdx.x < 2048) {
        int w    = threadIdx.x >> 6;
        int lane = threadIdx.x & 63;
        int row  = blockIdx.x * 4 + w;              // b*C + c
        const float4* xr = (const float4*)(x + (size_t)row * N);
        float s = 0.f;
        #pragma unroll
        for (int i = 0; i < 16; ++i) {
            float4 v = xr[i * 64 + lane];
            s += v.x + v.y + v.z + v.w;
        }
        #pragma unroll
        for (int off = 32; off; off >>= 1) s += __shfl_xor(s, off, 64);
        if (lane == 0) pooled[row] = s * (1.0f / N);
    } else {
        int idx = (blockIdx.x - 2048) * 256 + threadIdx.x;  // 0..8191
        int o  = idx >> 6;                                  // 0..127
        int g  = idx & 63;
        int ck = g >> 3;
        int c8 = (g & 7) * 8;
        int c  = ck * KC + c8;
        float inv = gamma[o] * rsqrtf(var[o] + 1e-5f);
        float4 a  = *(const float4*)(w3 + o * C + c);
        float4 bq = *(const float4*)(w3 + o * C + c + 4);
        unsigned r0 = f2bf(a.x * inv)  | (f2bf(a.y * inv) << 16);
        unsigned r1 = f2bf(a.z * inv)  | (f2bf(a.w * inv) << 16);
        unsigned r2 = f2bf(bq.x * inv) | (f2bf(bq.y * inv) << 16);
        unsigned r3 = f2bf(bq.z * inv) | (f2bf(bq.w * inv) << 16);
        int byte = (o * 128 + c8 * 2) ^ ((o & 7) << 4);
        *(uint4*)((char*)w3s + ck * 16384 + byte) = make_uint4(r0, r1, r2, r3);
        if (idx < CR) {
            float iv = gamma[idx] * rsqrtf(var[idx] + 1e-5f);
            bias2[idx] = b3[idx] * iv + beta[idx] - mean[idx] * iv;
        }
    }
}

// ---------------------------------------------------------------------------
// k_ca: channel-attention MLP.  One block (128 threads) per batch element.
// ---------------------------------------------------------------------------
__global__ __launch_bounds__(128) void k_ca(
    const float* __restrict__ pooled,
    const float* __restrict__ w1, const float* __restrict__ b1,
    const float* __restrict__ w2, const float* __restrict__ b2,
    float* __restrict__ ca)
{
    __shared__ float ps[C];
    __shared__ float hs[CR];
    int b = blockIdx.x, t = threadIdx.x;
    #pragma unroll
    for (int i = 0; i < 4; ++i) ps[t + i * 128] = pooled[b * C + t + i * 128];
    __syncthreads();

    float acc = b1[t];
    const float4* wr = (const float4*)(w1 + t * C);
    const float4* pr = (const float4*)ps;
    #pragma unroll 4
    for (int i = 0; i < C / 4; ++i) {
        float4 wv = wr[i], pv = pr[i];
        acc += wv.x * pv.x + wv.y * pv.y + wv.z * pv.z + wv.w * pv.w;
    }
    hs[t] = fmaxf(acc, 0.f);
    __syncthreads();

    #pragma unroll
    for (int k = 0; k < 4; ++k) {
        int c2 = t + k * 128;
        float a = b2[c2];
        const float4* w2r = (const float4*)(w2 + c2 * CR);
        const float4* hr  = (const float4*)hs;
        #pragma unroll 4
        for (int i = 0; i < CR / 4; ++i) {
            float4 wv = w2r[i], hv = hr[i];
            a += wv.x * hv.x + wv.y * hv.y + wv.z * hv.z + wv.w * hv.w;
        }
        ca[b * C + c2] = sigmoidf_(a);
    }
}

// ---------------------------------------------------------------------------
// k_main (bf16 MFMA, 2-phase prefetched): per (b, 64-col n-tile):
//   h2[128 o][64 n] = w3s @ (x*ca) over c=512 via mfma_f32_16x16x32_bf16
//   sa[n] = sigmoid(sum_o w4[o]*relu(h2+bias2) + b4)
//   out   = x * (1 + ca[c]*sa[n])
// K-loop: reg-stage chunk ck+1 loads BEFORE the pre-MFMA barrier; raw
// s_barrier + lgkmcnt(0) (no vmcnt drain) lets them fly across MFMA.
// ---------------------------------------------------------------------------
__global__ __launch_bounds__(256) void k_main(
    const float* __restrict__ x, const float* __restrict__ ca,
    const unsigned short* __restrict__ w3s, const float* __restrict__ bias2,
    const float* __restrict__ w4, const float* __restrict__ b4,
    float* __restrict__ out)
{
    __shared__ __align__(16) short lds_w[CR * KC];   // 16 KB, swizzled [o][c]
    __shared__ __align__(16) short lds_x[NT * KC];   //  8 KB, swizzled [n][c]
    __shared__ float ca_s[C];
    __shared__ __align__(16) float sa_s[NT];
    __shared__ float red[2][NT];
    __shared__ float bias2_s[CR];
    __shared__ float w4_s[CR];

    const int t    = threadIdx.x;
    const int lane = t & 63;
    const int w    = t >> 6;
    const int b    = blockIdx.y;
    const int n0   = blockIdx.x * NT;
    const int wo   = (w & 1) * 64;     // wave o-base
    const int wn   = (w >> 1) * 32;    // wave n-base

    ca_s[t]       = ca[b * C + t];
    ca_s[t + 256] = ca[b * C + t + 256];
    if (t < CR) { bias2_s[t] = bias2[t]; w4_s[t] = w4[t]; }

    const size_t xbase = (size_t)b * C * N + n0;
    const int ng = t & 31;   // x-stage: n pair = 2*ng
    const int cg = t >> 5;   // x-stage: c sub  = cg*8

    float2 xv[8];
    uint4  wv[4];

#define LOADX(CK) do { const int c0_ = (CK) * KC;                              \
    _Pragma("unroll") for (int ci = 0; ci < 8; ++ci)                           \
        xv[ci] = *(const float2*)(x + xbase + (size_t)(c0_ + cg * 8 + ci) * N + 2 * ng); \
} while (0)
#define LOADW(CK) do { const char* ws_ = (const char*)w3s + (CK) * 16384;      \
    _Pragma("unroll") for (int i = 0; i < 4; ++i)                              \
        wv[i] = *(const uint4*)(ws_ + i * 4096 + t * 16);                      \
} while (0)

    f32x4 acc[4][2];
    #pragma unroll
    for (int i = 0; i < 4; ++i) { acc[i][0] = (f32x4)0.f; acc[i][1] = (f32x4)0.f; }

    LOADX(0);
    LOADW(0);
    LGKM_BARRIER();           // ca_s/bias2_s visible

    for (int ck = 0; ck < C / KC; ++ck) {
        const int c0 = ck * KC;
        // ---- LDS write from staged regs (vmcnt waits inserted by compiler)
        #pragma unroll
        for (int i = 0; i < 4; ++i)
            *(uint4*)((char*)lds_w + i * 4096 + t * 16) = wv[i];
        {
            unsigned q0[4], q1[4];
            #pragma unroll
            for (int h = 0; h < 4; ++h) {
                float s0 = ca_s[c0 + cg * 8 + 2 * h];
                float s1 = ca_s[c0 + cg * 8 + 2 * h + 1];
                q0[h] = f2bf(xv[2 * h].x * s0) | (f2bf(xv[2 * h + 1].x * s1) << 16);
                q1[h] = f2bf(xv[2 * h].y * s0) | (f2bf(xv[2 * h + 1].y * s1) << 16);
            }
            int nl0 = 2 * ng, nl1 = 2 * ng + 1;
            int a0 = (nl0 * 128 + cg * 16) ^ ((nl0 & 7) << 4);
            int a1 = (nl1 * 128 + cg * 16) ^ ((nl1 & 7) << 4);
            *(uint4*)((char*)lds_x + a0) = make_uint4(q0[0], q0[1], q0[2], q0[3]);
            *(uint4*)((char*)lds_x + a1) = make_uint4(q1[0], q1[1], q1[2], q1[3]);
        }
        // ---- prefetch next chunk (in flight across MFMA phase)
        if (ck < C / KC - 1) {
            LOADX(ck + 1);
            LOADW(ck + 1);
        }
        LGKM_BARRIER();       // LDS ready; prefetch NOT drained
        // ---- 2 K-steps of 32
        #pragma unroll
        for (int kk = 0; kk < 2; ++kk) {
            bf16x8 af[4], bfr[2];
            #pragma unroll
            for (int i = 0; i < 4; ++i) {
                int ar = wo + i * 16 + (lane & 15);
                int ab = (ar * 128 + kk * 64 + (lane >> 4) * 16) ^ ((ar & 7) << 4);
                af[i] = *(const bf16x8*)((const char*)lds_w + ab);
            }
            #pragma unroll
            for (int j = 0; j < 2; ++j) {
                int br = wn + j * 16 + (lane & 15);
                int bb = (br * 128 + kk * 64 + (lane >> 4) * 16) ^ ((br & 7) << 4);
                bfr[j] = *(const bf16x8*)((const char*)lds_x + bb);
            }
            #pragma unroll
            for (int i = 0; i < 4; ++i)
                #pragma unroll
                for (int j = 0; j < 2; ++j)
                    acc[i][j] = __builtin_amdgcn_mfma_f32_16x16x32_bf16(af[i], bfr[j], acc[i][j], 0, 0, 0);
        }
        LGKM_BARRIER();       // frag reads retired; LDS safe to overwrite
    }

    // ---- sa: per-lane partial over this wave's 64 o's, then cross-lane
    // C/D layout: col = lane&15 (n), row = (lane>>4)*4 + reg (o)
    #pragma unroll
    for (int j = 0; j < 2; ++j) {
        float p = 0.f;
        #pragma unroll
        for (int i = 0; i < 4; ++i) {
            #pragma unroll
            for (int r = 0; r < 4; ++r) {
                int o = wo + i * 16 + (lane >> 4) * 4 + r;
                float hval = acc[i][j][r] + bias2_s[o];
                p = fmaf(w4_s[o], fmaxf(hval, 0.f), p);
            }
        }
        p += __shfl_xor(p, 16, 64);
        p += __shfl_xor(p, 32, 64);
        if (lane < 16) red[w & 1][wn + j * 16 + lane] = p;
    }
    __syncthreads();
    if (t < NT) sa_s[t] = sigmoidf_(red[0][t] + red[1][t] + b4[0]);
    __syncthreads();

    // ---- epilogue: out = x * (1 + ca[c]*sa[n]); x re-read is L2-hot
    #pragma unroll 4
    for (int it = 0; it < 32; ++it) {
        int f4 = it * 256 + t;          // 0..8191
        int c  = f4 >> 4;               // 0..511
        int n4 = f4 & 15;
        size_t off = xbase + (size_t)c * N + n4 * 4;
        float4 v = *(const float4*)(x + off);
        float cav = ca_s[c];
        float4 sv = *(const float4*)&sa_s[n4 * 4];
        float4 o4;
        o4.x = v.x * fmaf(cav, sv.x, 1.0f);
        o4.y = v.y * fmaf(cav, sv.y, 1.0f);
        o4.z = v.z * fmaf(cav, sv.z, 1.0f);
        o4.w = v.w * fmaf(cav, sv.w, 1.0f);
        *(float4*)(out + off) = o4;
    }
#undef LOADX
#undef LOADW
}

extern "C" void kernel_launch(void* const* d_in, const int* in_sizes, int n_in,
                              void* d_out, int out_size, void* d_ws, size_t ws_size,
                              hipStream_t stream)
{
    const float* x   = (const float*)d_in[0];
    const float* w1  = (const float*)d_in[1];
    const float* b1  = (const float*)d_in[2];
    const float* w2  = (const float*)d_in[3];
    const float* b2  = (const float*)d_in[4];
    const float* w3  = (const float*)d_in[5];
    const float* b3  = (const float*)d_in[6];
    const float* g   = (const float*)d_in[7];
    const float* be  = (const float*)d_in[8];
    const float* mn  = (const float*)d_in[9];
    const float* vr  = (const float*)d_in[10];
    const float* w4  = (const float*)d_in[11];
    const float* b4  = (const float*)d_in[12];
    float* out = (float*)d_out;

    float* ws     = (float*)d_ws;
    float* pooled = ws;                                  // 8192 floats
    float* ca     = ws + 8192;                           // 8192 floats
    float* bias2  = ws + 16384;                          // 128 floats (+pad)
    unsigned short* w3s = (unsigned short*)(ws + 16640); // 65536 bf16 (128 KB)

    k_pre<<<2048 + 32, 256, 0, stream>>>(x, pooled, w3, b3, g, be, mn, vr, w3s, bias2);
    k_ca<<<B, 128, 0, stream>>>(pooled, w1, b1, w2, b2, ca);
    dim3 g3(N / NT, B);
    k_main<<<g3, 256, 0, stream>>>(x, ca, w3s, bias2, w4, b4, out);
}

// Round 5
// 119.925 us; speedup vs baseline: 1.1756x; 1.1756x over previous
//
#include <hip/hip_runtime.h>
#include <math.h>

// Shapes fixed by the reference: x [B=16, C=512, N=4096] fp32.
constexpr int B  = 16;
constexpr int C  = 512;
constexpr int N  = 4096;
constexpr int CR = 128;   // C/4
constexpr int NT = 64;    // n-tile per k_main block
constexpr int KC = 64;    // c-chunk per staging step

typedef __attribute__((ext_vector_type(8))) short bf16x8;
typedef __attribute__((ext_vector_type(4))) float f32x4;

__device__ __forceinline__ float sigmoidf_(float v) {
    return 1.0f / (1.0f + __expf(-v));
}
// fp32 -> bf16 round-to-nearest-even
__device__ __forceinline__ unsigned f2bf(float f) {
    unsigned u = __float_as_uint(f);
    u += 0x7fffu + ((u >> 16) & 1u);
    return u >> 16;
}

// lgkmcnt(0) + raw barrier: LDS writes visible WITHOUT draining vmcnt,
// so in-flight global prefetches survive the barrier (anti-m97-stall).
#define LGKM_BARRIER() do {                                   \
    asm volatile("s_waitcnt lgkmcnt(0)" ::: "memory");        \
    __builtin_amdgcn_s_barrier();                             \
    asm volatile("" ::: "memory");                            \
} while (0)

// ---------------------------------------------------------------------------
// k_pre: fused  (blocks 0..2047)  pooled[b][c] = mean_n x[b][c][n]
//               (blocks 2048..2079) BN-fold w3 -> bf16 in MFMA A-FRAGMENT
//               lane order + bias2.
// w3f layout: group g = ck*16 + kk*8 + ob   (ck c-chunk, kk 32-c half, ob o/16)
//   byte(g, lane) = (g*64 + lane)*16 ; content = w[ob*16+(lane&15)]
//                   [ck*64 + kk*32 + (lane>>4)*8 + 0..7] (8 bf16, c ascending)
// ---------------------------------------------------------------------------
__global__ __launch_bounds__(256) void k_pre(
    const float* __restrict__ x, float* __restrict__ pooled,
    const float* __restrict__ w3, const float* __restrict__ b3,
    const float* __restrict__ gamma, const float* __restrict__ beta,
    const float* __restrict__ mean, const float* __restrict__ var,
    unsigned short* __restrict__ w3f, float* __restrict__ bias2)
{
    if (blockIdx.x < 2048) {
        int w    = threadIdx.x >> 6;
        int lane = threadIdx.x & 63;
        int row  = blockIdx.x * 4 + w;              // b*C + c
        const float4* xr = (const float4*)(x + (size_t)row * N);
        float s = 0.f;
        #pragma unroll
        for (int i = 0; i < 16; ++i) {
            float4 v = xr[i * 64 + lane];
            s += v.x + v.y + v.z + v.w;
        }
        #pragma unroll
        for (int off = 32; off; off >>= 1) s += __shfl_xor(s, off, 64);
        if (lane == 0) pooled[row] = s * (1.0f / N);
    } else {
        int idx  = (blockIdx.x - 2048) * 256 + threadIdx.x;  // 0..8191
        int g    = idx >> 6;          // fragment group 0..127
        int lane = idx & 63;
        int ck   = g >> 4;
        int kk   = (g >> 3) & 1;
        int ob   = g & 7;
        int o    = ob * 16 + (lane & 15);
        int c    = ck * 64 + kk * 32 + (lane >> 4) * 8;
        float inv = gamma[o] * rsqrtf(var[o] + 1e-5f);
        float4 a  = *(const float4*)(w3 + o * C + c);
        float4 bq = *(const float4*)(w3 + o * C + c + 4);
        unsigned r0 = f2bf(a.x * inv)  | (f2bf(a.y * inv) << 16);
        unsigned r1 = f2bf(a.z * inv)  | (f2bf(a.w * inv) << 16);
        unsigned r2 = f2bf(bq.x * inv) | (f2bf(bq.y * inv) << 16);
        unsigned r3 = f2bf(bq.z * inv) | (f2bf(bq.w * inv) << 16);
        *(uint4*)((char*)w3f + (size_t)idx * 16) = make_uint4(r0, r1, r2, r3);
        if (idx < CR) {
            float iv = gamma[idx] * rsqrtf(var[idx] + 1e-5f);
            bias2[idx] = b3[idx] * iv + beta[idx] - mean[idx] * iv;
        }
    }
}

// ---------------------------------------------------------------------------
// k_ca: channel-attention MLP.  One block (128 threads) per batch element.
// ---------------------------------------------------------------------------
__global__ __launch_bounds__(128) void k_ca(
    const float* __restrict__ pooled,
    const float* __restrict__ w1, const float* __restrict__ b1,
    const float* __restrict__ w2, const float* __restrict__ b2,
    float* __restrict__ ca)
{
    __shared__ float ps[C];
    __shared__ float hs[CR];
    int b = blockIdx.x, t = threadIdx.x;
    #pragma unroll
    for (int i = 0; i < 4; ++i) ps[t + i * 128] = pooled[b * C + t + i * 128];
    __syncthreads();

    float acc = b1[t];
    const float4* wr = (const float4*)(w1 + t * C);
    const float4* pr = (const float4*)ps;
    #pragma unroll 4
    for (int i = 0; i < C / 4; ++i) {
        float4 wv = wr[i], pv = pr[i];
        acc += wv.x * pv.x + wv.y * pv.y + wv.z * pv.z + wv.w * pv.w;
    }
    hs[t] = fmaxf(acc, 0.f);
    __syncthreads();

    #pragma unroll
    for (int k = 0; k < 4; ++k) {
        int c2 = t + k * 128;
        float a = b2[c2];
        const float4* w2r = (const float4*)(w2 + c2 * CR);
        const float4* hr  = (const float4*)hs;
        #pragma unroll 4
        for (int i = 0; i < CR / 4; ++i) {
            float4 wv = w2r[i], hv = hr[i];
            a += wv.x * hv.x + wv.y * hv.y + wv.z * hv.z + wv.w * hv.w;
        }
        ca[b * C + c2] = sigmoidf_(a);
    }
}

// ---------------------------------------------------------------------------
// k_main: per (b, 64-col n-tile):
//   h2[128 o][64 n] = W @ (x*ca) over c=512 via mfma_f32_16x16x32_bf16
//   sa[n] = sigmoid(sum_o w4[o]*relu(h2+bias2) + b4);  out = x*(1+ca*sa)
// A-fragments loaded DIRECTLY from global (w3f, lane-ordered, L2-resident) —
// no W staging regs/LDS.  x-tile double-buffered in LDS, 2-deep reg prefetch
// (xva/xvb), one lgkm-only barrier per chunk; ck-loop fully unrolled.
// ---------------------------------------------------------------------------
__global__ __launch_bounds__(256, 2) void k_main(
    const float* __restrict__ x, const float* __restrict__ ca,
    const unsigned short* __restrict__ w3f, const float* __restrict__ bias2,
    const float* __restrict__ w4, const float* __restrict__ b4,
    float* __restrict__ out)
{
    __shared__ __align__(16) short lds_x[2][NT * KC];   // 2 x 8 KB, swizzled [n][c]
    __shared__ float ca_s[C];
    __shared__ __align__(16) float sa_s[NT];
    __shared__ float red[2][NT];
    __shared__ float bias2_s[CR];
    __shared__ float w4_s[CR];

    const int t    = threadIdx.x;
    const int lane = t & 63;
    const int w    = t >> 6;
    const int b    = blockIdx.y;
    const int n0   = blockIdx.x * NT;
    const int wo   = (w & 1) * 64;     // wave o-base
    const int wn   = (w >> 1) * 32;    // wave n-base
    const int ob0  = wo >> 4;

    const size_t xbase = (size_t)b * C * N + n0;
    const int ng = t & 31;   // x-stage: n pair = 2*ng
    const int cg = t >> 5;   // x-stage: c sub  = cg*8

    float2 xva[8], xvb[8];

#define LOADX(dst, CK) do { const int c0_ = (CK) * KC;                         \
    _Pragma("unroll") for (int ci = 0; ci < 8; ++ci)                           \
        dst[ci] = *(const float2*)(x + xbase + (size_t)(c0_ + cg * 8 + ci) * N + 2 * ng); \
} while (0)

#define CONVERT_WRITE(src, CK, BUF) do { const int c0_ = (CK) * KC;            \
    unsigned q0[4], q1[4];                                                     \
    _Pragma("unroll") for (int h = 0; h < 4; ++h) {                            \
        float s0 = ca_s[c0_ + cg * 8 + 2 * h];                                 \
        float s1 = ca_s[c0_ + cg * 8 + 2 * h + 1];                             \
        q0[h] = f2bf(src[2 * h].x * s0) | (f2bf(src[2 * h + 1].x * s1) << 16); \
        q1[h] = f2bf(src[2 * h].y * s0) | (f2bf(src[2 * h + 1].y * s1) << 16); \
    }                                                                          \
    int nl0 = 2 * ng, nl1 = 2 * ng + 1;                                        \
    int a0 = (nl0 * 128 + cg * 16) ^ ((nl0 & 7) << 4);                         \
    int a1 = (nl1 * 128 + cg * 16) ^ ((nl1 & 7) << 4);                         \
    *(uint4*)((char*)lds_x[BUF] + a0) = make_uint4(q0[0], q0[1], q0[2], q0[3]);\
    *(uint4*)((char*)lds_x[BUF] + a1) = make_uint4(q1[0], q1[1], q1[2], q1[3]);\
} while (0)

    // prologue: get the first two x chunks in flight immediately
    LOADX(xva, 0);
    LOADX(xvb, 1);

    ca_s[t]       = ca[b * C + t];
    ca_s[t + 256] = ca[b * C + t + 256];
    if (t < CR) { bias2_s[t] = bias2[t]; w4_s[t] = w4[t]; }
    LGKM_BARRIER();                 // ca_s visible (vmcnt NOT drained)

    CONVERT_WRITE(xva, 0, 0);       // chunk 0 -> buf 0

    f32x4 acc[4][2];
    #pragma unroll
    for (int i = 0; i < 4; ++i) { acc[i][0] = (f32x4)0.f; acc[i][1] = (f32x4)0.f; }

    const char* wf = (const char*)w3f;

    #pragma unroll
    for (int ck = 0; ck < 8; ++ck) {
        // A-fragments straight from global (L2-hot, coalesced lane*16)
        bf16x8 af[2][4];
        #pragma unroll
        for (int kk = 0; kk < 2; ++kk)
            #pragma unroll
            for (int i = 0; i < 4; ++i) {
                int g = ck * 16 + kk * 8 + ob0 + i;
                af[kk][i] = *(const bf16x8*)(wf + (size_t)(g * 64 + lane) * 16);
            }
        // prefetch x chunk ck+2 into the set freed one iteration ago
        if (ck < 6) { if (ck & 1) LOADX(xvb, ck + 2); else LOADX(xva, ck + 2); }

        LGKM_BARRIER();             // buf(ck&1) visible to all waves

        #pragma unroll
        for (int kk = 0; kk < 2; ++kk) {
            bf16x8 bfr[2];
            #pragma unroll
            for (int j = 0; j < 2; ++j) {
                int br = wn + j * 16 + (lane & 15);
                int bb = (br * 128 + kk * 64 + (lane >> 4) * 16) ^ ((br & 7) << 4);
                bfr[j] = *(const bf16x8*)((const char*)lds_x[ck & 1] + bb);
            }
            #pragma unroll
            for (int i = 0; i < 4; ++i)
                #pragma unroll
                for (int j = 0; j < 2; ++j)
                    acc[i][j] = __builtin_amdgcn_mfma_f32_16x16x32_bf16(af[kk][i], bfr[j], acc[i][j], 0, 0, 0);
        }
        // convert chunk ck+1 (loaded last iteration) into the other buffer
        if (ck < 7) { if (ck & 1) CONVERT_WRITE(xva, ck + 1, 0); else CONVERT_WRITE(xvb, ck + 1, 1); }
    }

    // ---- sa: per-lane partial over this wave's 64 o's, then cross-lane
    // C/D layout: col = lane&15 (n), row = (lane>>4)*4 + reg (o)
    #pragma unroll
    for (int j = 0; j < 2; ++j) {
        float p = 0.f;
        #pragma unroll
        for (int i = 0; i < 4; ++i) {
            #pragma unroll
            for (int r = 0; r < 4; ++r) {
                int o = wo + i * 16 + (lane >> 4) * 4 + r;
                float hval = acc[i][j][r] + bias2_s[o];
                p = fmaf(w4_s[o], fmaxf(hval, 0.f), p);
            }
        }
        p += __shfl_xor(p, 16, 64);
        p += __shfl_xor(p, 32, 64);
        if (lane < 16) red[w & 1][wn + j * 16 + lane] = p;
    }
    __syncthreads();
    if (t < NT) sa_s[t] = sigmoidf_(red[0][t] + red[1][t] + b4[0]);
    __syncthreads();

    // ---- epilogue: out = x * (1 + ca[c]*sa[n]); x re-read is L1/L2-hot
    #pragma unroll 4
    for (int it = 0; it < 32; ++it) {
        int f4 = it * 256 + t;          // 0..8191
        int c  = f4 >> 4;               // 0..511
        int n4 = f4 & 15;
        size_t off = xbase + (size_t)c * N + n4 * 4;
        float4 v = *(const float4*)(x + off);
        float cav = ca_s[c];
        float4 sv = *(const float4*)&sa_s[n4 * 4];
        float4 o4;
        o4.x = v.x * fmaf(cav, sv.x, 1.0f);
        o4.y = v.y * fmaf(cav, sv.y, 1.0f);
        o4.z = v.z * fmaf(cav, sv.z, 1.0f);
        o4.w = v.w * fmaf(cav, sv.w, 1.0f);
        *(float4*)(out + off) = o4;
    }
#undef LOADX
#undef CONVERT_WRITE
}

extern "C" void kernel_launch(void* const* d_in, const int* in_sizes, int n_in,
                              void* d_out, int out_size, void* d_ws, size_t ws_size,
                              hipStream_t stream)
{
    const float* x   = (const float*)d_in[0];
    const float* w1  = (const float*)d_in[1];
    const float* b1  = (const float*)d_in[2];
    const float* w2  = (const float*)d_in[3];
    const float* b2  = (const float*)d_in[4];
    const float* w3  = (const float*)d_in[5];
    const float* b3  = (const float*)d_in[6];
    const float* g   = (const float*)d_in[7];
    const float* be  = (const float*)d_in[8];
    const float* mn  = (const float*)d_in[9];
    const float* vr  = (const float*)d_in[10];
    const float* w4  = (const float*)d_in[11];
    const float* b4  = (const float*)d_in[12];
    float* out = (float*)d_out;

    float* ws     = (float*)d_ws;
    float* pooled = ws;                                  // 8192 floats
    float* ca     = ws + 8192;                           // 8192 floats
    float* bias2  = ws + 16384;                          // 128 floats (+pad)
    unsigned short* w3f = (unsigned short*)(ws + 16640); // 65536 bf16 (128 KB), frag-ordered

    k_pre<<<2048 + 32, 256, 0, stream>>>(x, pooled, w3, b3, g, be, mn, vr, w3f, bias2);
    k_ca<<<B, 128, 0, stream>>>(pooled, w1, b1, w2, b2, ca);
    dim3 g3(N / NT, B);
    k_main<<<g3, 256, 0, stream>>>(x, ca, w3f, bias2, w4, b4, out);
}